// Round 13
// baseline (525.210 us; speedup 1.0000x reference)
//
#include <hip/hip_runtime.h>
#include <math.h>

#define B_ 2
#define N_ 4100
#define C_ 768
#define T_ 4
#define H_ 12
#define D_ 64
#define M_ 4096
#define S_ 48          // T_*H_
#define KS_ 12         // k-split for score GEMM
#define KC_ 64         // channels per k-split chunk
#define MT_ 128        // m rows per score block
#define SEG_ 8         // m-segments per (b,s) in reduce
#define SCALE 0.125f   // d^-0.5 = 1/8

// ---- top-2 helpers (ties -> lowest index, matching jax.lax.top_k) ----
__device__ __forceinline__ bool better(float va, int ia, float vb, int ib) {
  return (va > vb) || (va == vb && ia < ib);
}

__device__ __forceinline__ void merge2(float& v1, int& i1, float& v2, int& i2,
                                       float ov1, int oi1, float ov2, int oi2) {
  if (better(ov1, oi1, v1, i1)) {
    float tv; int ti;
    tv = v1; ti = i1; v1 = ov1; i1 = oi1; ov1 = tv; oi1 = ti;
    tv = v2; ti = i2; v2 = ov2; i2 = oi2; ov2 = tv; oi2 = ti;
  }
  if (better(ov1, oi1, v2, i2)) { v2 = ov1; i2 = oi1; }
}

// ---- K1: qk only (out arrives zeroed by the harness each iteration).
// qk[b*S+s][c] = sum_j q[b,s,j] * kv_w[j][c] * SCALE  (k-proj folded into q)
__global__ __launch_bounds__(256) void qk_kernel(const float* __restrict__ x,
    const float* __restrict__ qs_w, const float* __restrict__ kv_w,
    float* __restrict__ qk) {
  const int blk = blockIdx.x;
  const int tid = threadIdx.x;
  const int h = blk % H_;
  const int t = (blk / H_) % T_;
  const int b = blk / S_;
  __shared__ float xs[C_];
  __shared__ float red[256];
  __shared__ float qseg[D_];
  for (int i = tid; i < C_; i += 256) xs[i] = x[((size_t)b * N_ + t) * C_ + i];
  __syncthreads();
  {
    const int j = tid & 63;
    const int pt = tid >> 6;          // 4 parts of 192 channels
    const float* wr = qs_w + ((size_t)t * C_ + h * D_ + j) * C_ + pt * 192;
    float a = 0.f;
    for (int c = 0; c < 192; ++c) a += xs[pt * 192 + c] * wr[c];
    red[tid] = a;
  }
  __syncthreads();
  if (tid < 64)
    qseg[tid] = (red[tid] + red[tid + 64] + red[tid + 128] + red[tid + 192]) * SCALE;
  __syncthreads();
  for (int c = tid; c < C_; c += 256) {
    float a = 0.f;
    #pragma unroll 8
    for (int j = 0; j < 64; ++j) a += qseg[j] * kv_w[((size_t)(h * D_ + j)) * C_ + c];
    qk[(size_t)blk * C_ + c] = a;
  }
}

// ---- K2: partial scores, channel-quartered double-buffered staging.
// block = (b, mtile of 128 m) x kc (12 splits of 64 ch); grid 768 = 3/CU.
// KC=64 split into 4 quarters of 16 ch; 2 LDS buffers (26.6 KB total).
// Per quarter: issue next-quarter global loads to regs -> compute current
// quarter (~768 cyc/wave hides HBM latency) -> barrier -> reg->LDS -> barrier.
// Only quarter 0's stage is exposed (was: full 64-ch stage serialized).
// fbuf row stride 20 floats (20%8==4) -> per-lane b128 reads conflict-free.
__global__ __launch_bounds__(256, 3) void score_kernel(const float* __restrict__ x,
    const float* __restrict__ qk, float* __restrict__ part) {
  const int bm = blockIdx.x & 31;
  const int b  = blockIdx.x >> 5;
  const int kc = blockIdx.y;          // 0..11
  const int tid = threadIdx.x;

  __shared__ __align__(16) float fbuf[2][MT_][20];   // 2 x 128 rows x 16 ch (+4 pad)
  __shared__ __align__(16) float qbuf[2][S_][16];    // 2 x 48 x 16 ch

  const char* xb = (const char*)(x + ((size_t)b * N_ + T_ + bm * MT_) * C_ + kc * KC_);
  const char* qb = (const char*)(qk + (size_t)b * S_ * C_ + kc * KC_);

  // per-thread load slots: f = 512 float4/quarter (2/thread), q = 192 (tid<192)
  const unsigned fr0 = tid >> 2,          fj0 = tid & 3;
  const unsigned fr1 = (256 + tid) >> 2,  fj1 = tid & 3;   // (256+tid)&3 == tid&3
  const unsigned qs  = tid >> 2,          qj  = tid & 3;   // valid if tid < 192

  float4 fA, fB, qA;
  // ---- load quarter 0, write buf0 ----
  fA = *(const float4*)(xb + (size_t)fr0 * (C_ * 4) + (fj0 * 16));
  fB = *(const float4*)(xb + (size_t)fr1 * (C_ * 4) + (fj1 * 16));
  if (tid < 192) qA = *(const float4*)(qb + (size_t)qs * (C_ * 4) + (qj * 16));
  *(float4*)&fbuf[0][fr0][fj0 * 4] = fA;
  *(float4*)&fbuf[0][fr1][fj1 * 4] = fB;
  if (tid < 192) *(float4*)&qbuf[0][qs][qj * 4] = qA;
  // ---- issue quarter 1 ----
  fA = *(const float4*)(xb + (size_t)fr0 * (C_ * 4) + (64 + fj0 * 16));
  fB = *(const float4*)(xb + (size_t)fr1 * (C_ * 4) + (64 + fj1 * 16));
  if (tid < 192) qA = *(const float4*)(qb + (size_t)qs * (C_ * 4) + (64 + qj * 16));
  __syncthreads();

  const int w = tid >> 6;
  const int lane = tid & 63;
  const int s0 = w * 12;               // this wave's s range

  float acc[12][2];
  #pragma unroll
  for (int si = 0; si < 12; ++si) {
    acc[si][0] = 0.f; acc[si][1] = 0.f;
  }

  #pragma unroll
  for (int h = 0; h < 4; ++h) {
    const int cb = h & 1;
    // compute quarter h (4 j-steps of 4 ch)
    #pragma unroll
    for (int j = 0; j < 4; ++j) {
      float4 f0 = *(const float4*)&fbuf[cb][lane     ][j * 4];
      float4 f1 = *(const float4*)&fbuf[cb][lane + 64][j * 4];
      #pragma unroll
      for (int si = 0; si < 12; ++si) {
        float4 q = *(const float4*)&qbuf[cb][s0 + si][j * 4];
        acc[si][0] += f0.x * q.x + f0.y * q.y + f0.z * q.z + f0.w * q.w;
        acc[si][1] += f1.x * q.x + f1.y * q.y + f1.z * q.z + f1.w * q.w;
      }
    }
    if (h < 3) {
      __syncthreads();                 // all waves done reading buf[(h+1)&1]'s old data
      const int nb = (h + 1) & 1;
      *(float4*)&fbuf[nb][fr0][fj0 * 4] = fA;
      *(float4*)&fbuf[nb][fr1][fj1 * 4] = fB;
      if (tid < 192) *(float4*)&qbuf[nb][qs][qj * 4] = qA;
      if (h + 2 < 4) {                 // issue quarter h+2
        fA = *(const float4*)(xb + (size_t)fr0 * (C_ * 4) + ((h + 2) * 64 + fj0 * 16));
        fB = *(const float4*)(xb + (size_t)fr1 * (C_ * 4) + ((h + 2) * 64 + fj1 * 16));
        if (tid < 192) qA = *(const float4*)(qb + (size_t)qs * (C_ * 4) + ((h + 2) * 64 + qj * 16));
      }
      __syncthreads();                 // buf[(h+1)&1] ready
    }
  }

  const int m0 = bm * MT_;
  #pragma unroll
  for (int si = 0; si < 12; ++si) {
    float* pp = part + (((size_t)kc * B_ + b) * S_ + (s0 + si)) * M_ + m0 + lane;
    pp[0]  = acc[si][0];
    pp[64] = acc[si][1];
  }
}

// ---- K3: sum k-split partials over a 512-m segment + segment top-2 candidate.
// block = (b*S+s)*8 + seg; 256 threads, 2 m each.
__global__ __launch_bounds__(256) void reduce_kernel(const float* __restrict__ part,
                                                     float* __restrict__ cand) {
  const int seg = blockIdx.x & 7;
  const int bs = blockIdx.x >> 3;     // b*S + s
  const int tid = threadIdx.x;
  const size_t kstride = (size_t)B_ * S_ * M_;
  const float* p0 = part + (size_t)bs * M_ + seg * 512 + tid * 2;
  float a0 = 0.f, a1 = 0.f;
  #pragma unroll
  for (int kc = 0; kc < KS_; ++kc) {
    float2 v = *(const float2*)(p0 + kc * kstride);
    a0 += v.x; a1 += v.y;
  }
  const int mA = seg * 512 + tid * 2;
  float v1, v2; int i1, i2;
  if (better(a0, mA, a1, mA + 1)) { v1 = a0; i1 = mA; v2 = a1; i2 = mA + 1; }
  else                            { v1 = a1; i1 = mA + 1; v2 = a0; i2 = mA; }
  #pragma unroll
  for (int off = 1; off < 64; off <<= 1) {
    float ov1 = __shfl_xor(v1, off);
    int   oi1 = __shfl_xor(i1, off);
    float ov2 = __shfl_xor(v2, off);
    int   oi2 = __shfl_xor(i2, off);
    merge2(v1, i1, v2, i2, ov1, oi1, ov2, oi2);
  }
  __shared__ float cbuf[4][4];
  const int w = tid >> 6, lane = tid & 63;
  if (lane == 0) {
    cbuf[w][0] = v1; ((int*)cbuf[w])[1] = i1;
    cbuf[w][2] = v2; ((int*)cbuf[w])[3] = i2;
  }
  __syncthreads();
  if (tid == 0) {
    for (int ww = 1; ww < 4; ++ww)
      merge2(v1, i1, v2, i2, cbuf[ww][0], ((int*)cbuf[ww])[1],
             cbuf[ww][2], ((int*)cbuf[ww])[3]);
    ((float4*)cand)[blockIdx.x] =
        make_float4(v1, __int_as_float(i1), v2, __int_as_float(i2));
  }
}

// ---- K4a: merge 8 candidates -> top-2 + softmax; v-projection on combined
// row. Writes selws[bs*72 + {0..63: attnh, 64..67: i1,i2,w1,w2}].
// block = (b,s), 96 blocks.
__global__ __launch_bounds__(256) void gatherA_kernel(const float* __restrict__ x,
    const float* __restrict__ kv_w, const float* __restrict__ cand,
    float* __restrict__ selws) {
  const int h = blockIdx.x % H_;
  const int b = blockIdx.x / S_;
  const int tid = threadIdx.x;

  __shared__ __align__(16) float fc[C_];
  __shared__ float red[256];
  __shared__ float sel[4];

  if (tid < 8) {
    float4 cv = ((const float4*)cand)[blockIdx.x * 8 + tid];
    float v1 = cv.x, v2 = cv.z;
    int i1 = __float_as_int(cv.y), i2 = __float_as_int(cv.w);
    #pragma unroll
    for (int off = 1; off < 8; off <<= 1) {
      float ov1 = __shfl_xor(v1, off);
      int   oi1 = __shfl_xor(i1, off);
      float ov2 = __shfl_xor(v2, off);
      int   oi2 = __shfl_xor(i2, off);
      merge2(v1, i1, v2, i2, ov1, oi1, ov2, oi2);
    }
    if (tid == 0) {
      float w1 = 1.f / (1.f + expf(v2 - v1));
      ((int*)sel)[0] = i1; ((int*)sel)[1] = i2;
      sel[2] = w1; sel[3] = 1.f - w1;
    }
  }
  __syncthreads();
  const int i1 = ((const int*)sel)[0];
  const int i2 = ((const int*)sel)[1];
  const float w1 = sel[2], w2 = sel[3];

  const float* r0 = x + ((size_t)b * N_ + T_ + i1) * C_;
  const float* r1 = x + ((size_t)b * N_ + T_ + i2) * C_;
  for (int i = tid; i < C_; i += 256)
    fc[i] = w1 * r0[i] + w2 * r1[i];
  __syncthreads();

  {
    const int j = tid & 63, pt = tid >> 6;
    const float4* kr4 = (const float4*)(kv_w + ((size_t)(C_ + h * D_ + j)) * C_ + pt * 192);
    const float4* fc4 = (const float4*)(&fc[pt * 192]);
    float a = 0.f;
    #pragma unroll 8
    for (int c4 = 0; c4 < 48; ++c4) {
      float4 kv = kr4[c4], fv = fc4[c4];
      a += kv.x * fv.x + kv.y * fv.y + kv.z * fv.z + kv.w * fv.w;
    }
    red[tid] = a;
  }
  __syncthreads();
  if (tid < 64)
    selws[(size_t)blockIdx.x * 72 + tid] =
        red[tid] + red[tid + 64] + red[tid + 128] + red[tid + 192];
  else if (tid < 68)
    selws[(size_t)blockIdx.x * 72 + tid] = sel[tid - 64];
}

// ---- K4b: scatter. block = (bs, oc of 8); 96 outputs each.
// token + feature contributions via atomics (out zeroed by harness).
__global__ __launch_bounds__(256) void scatter_kernel(const float* __restrict__ x,
    const float* __restrict__ experts_w, const float* __restrict__ selws,
    float* __restrict__ out) {
  const int bs = blockIdx.x >> 3, oc = blockIdx.x & 7;
  const int h = bs % H_;
  const int t = (bs / H_) % T_;
  const int b = bs / S_;
  const int tid = threadIdx.x;

  __shared__ __align__(16) float attnh[D_], g0s[D_], g1s[D_];
  __shared__ float psel[4];

  if (tid < 4) psel[tid] = selws[(size_t)bs * 72 + 64 + tid];
  __syncthreads();
  const int i1 = __float_as_int(psel[0]);
  const int i2 = __float_as_int(psel[1]);
  const float w1 = psel[2], w2 = psel[3];

  if (tid < 64) {
    attnh[tid] = selws[(size_t)bs * 72 + tid];
    g0s[tid] = x[((size_t)b * N_ + T_ + i1) * C_ + h * D_ + tid];
    g1s[tid] = x[((size_t)b * N_ + T_ + i2) * C_ + h * D_ + tid];
  }
  __syncthreads();

  if (tid < 96) {
    const int o = oc * 96 + tid;
    const float4* er4 = (const float4*)(experts_w + ((size_t)t * C_ + o) * C_ + h * D_);
    const float4* at4 = (const float4*)attnh;
    const float4* g04 = (const float4*)g0s;
    const float4* g14 = (const float4*)g1s;
    float at = 0.f, a0 = 0.f, a1 = 0.f;
    #pragma unroll
    for (int c4 = 0; c4 < 16; ++c4) {
      float4 e = er4[c4];
      float4 av = at4[c4], v0 = g04[c4], v1 = g14[c4];
      at += e.x * av.x + e.y * av.y + e.z * av.z + e.w * av.w;
      a0 += e.x * v0.x + e.y * v0.y + e.z * v0.z + e.w * v0.w;
      a1 += e.x * v1.x + e.y * v1.y + e.z * v1.z + e.w * v1.w;
    }
    atomicAdd(&out[((size_t)b * N_ + t) * C_ + o], at);
    atomicAdd(&out[((size_t)b * N_ + T_ + i1) * C_ + o], w1 * a0);
    atomicAdd(&out[((size_t)b * N_ + T_ + i2) * C_ + o], w2 * a1);
  }
}

extern "C" void kernel_launch(void* const* d_in, const int* in_sizes, int n_in,
                              void* d_out, int out_size, void* d_ws, size_t ws_size,
                              hipStream_t stream) {
  const float* x         = (const float*)d_in[0];
  const float* qs_w      = (const float*)d_in[1];
  const float* kv_w      = (const float*)d_in[2];
  const float* experts_w = (const float*)d_in[3];
  float* out = (float*)d_out;

  float* ws    = (float*)d_ws;
  float* qk    = ws;                                  // B*S*C     = 73728 floats
  float* part  = qk + (size_t)B_ * S_ * C_;           // KS*B*S*M  = 4718592
  float* cand  = part + (size_t)KS_ * B_ * S_ * M_;   // B*S*SEG*4 = 3072
  float* selws = cand + (size_t)B_ * S_ * SEG_ * 4;   // B*S*72    = 6912

  hipLaunchKernelGGL(qk_kernel,      dim3(B_ * S_),        dim3(256), 0, stream, x, qs_w, kv_w, qk);
  hipLaunchKernelGGL(score_kernel,   dim3(B_ * 32, KS_),   dim3(256), 0, stream, x, qk, part);
  hipLaunchKernelGGL(reduce_kernel,  dim3(B_ * S_ * SEG_), dim3(256), 0, stream, part, cand);
  hipLaunchKernelGGL(gatherA_kernel, dim3(B_ * S_),        dim3(256), 0, stream, x, kv_w, cand, selws);
  hipLaunchKernelGGL(scatter_kernel, dim3(B_ * S_ * 8),    dim3(256), 0, stream, x, experts_w, selws, out);
}

// Round 14
// 143.860 us; speedup vs baseline: 3.6508x; 3.6508x over previous
//
#include <hip/hip_runtime.h>
#include <math.h>

#define B_ 2
#define N_ 4100
#define C_ 768
#define T_ 4
#define H_ 12
#define D_ 64
#define M_ 4096
#define S_ 48          // T_*H_
#define KS_ 12         // k-split for score GEMM
#define KC_ 64         // channels per k-split chunk
#define MT_ 128        // m rows per score block
#define SEG_ 8         // m-segments per (b,s) in reduce
#define SCALE 0.125f   // d^-0.5 = 1/8

// ---- top-2 helpers (ties -> lowest index, matching jax.lax.top_k) ----
__device__ __forceinline__ bool better(float va, int ia, float vb, int ib) {
  return (va > vb) || (va == vb && ia < ib);
}

__device__ __forceinline__ void merge2(float& v1, int& i1, float& v2, int& i2,
                                       float ov1, int oi1, float ov2, int oi2) {
  if (better(ov1, oi1, v1, i1)) {
    float tv; int ti;
    tv = v1; ti = i1; v1 = ov1; i1 = oi1; ov1 = tv; oi1 = ti;
    tv = v2; ti = i2; v2 = ov2; i2 = oi2; ov2 = tv; oi2 = ti;
  }
  if (better(ov1, oi1, v2, i2)) { v2 = ov1; i2 = oi1; }
}

// ---- K1: qk only (out arrives zeroed by the harness each iteration).
// qk[b*S+s][c] = sum_j q[b,s,j] * kv_w[j][c] * SCALE  (k-proj folded into q)
__global__ __launch_bounds__(256) void qk_kernel(const float* __restrict__ x,
    const float* __restrict__ qs_w, const float* __restrict__ kv_w,
    float* __restrict__ qk) {
  const int blk = blockIdx.x;
  const int tid = threadIdx.x;
  const int h = blk % H_;
  const int t = (blk / H_) % T_;
  const int b = blk / S_;
  __shared__ float xs[C_];
  __shared__ float red[256];
  __shared__ float qseg[D_];
  for (int i = tid; i < C_; i += 256) xs[i] = x[((size_t)b * N_ + t) * C_ + i];
  __syncthreads();
  {
    const int j = tid & 63;
    const int pt = tid >> 6;          // 4 parts of 192 channels
    const float* wr = qs_w + ((size_t)t * C_ + h * D_ + j) * C_ + pt * 192;
    float a = 0.f;
    for (int c = 0; c < 192; ++c) a += xs[pt * 192 + c] * wr[c];
    red[tid] = a;
  }
  __syncthreads();
  if (tid < 64)
    qseg[tid] = (red[tid] + red[tid + 64] + red[tid + 128] + red[tid + 192]) * SCALE;
  __syncthreads();
  for (int c = tid; c < C_; c += 256) {
    float a = 0.f;
    #pragma unroll 8
    for (int j = 0; j < 64; ++j) a += qseg[j] * kv_w[((size_t)(h * D_ + j)) * C_ + c];
    qk[(size_t)blk * C_ + c] = a;
  }
}

// ---- K2: partial scores, f half-tile double-buffered (register-light).
// block = (b, mtile of 128 m) x kc (12 splits of 64 ch); grid 768 = 3/CU.
// q staged ONCE (read-only, 13 KB). f staged in two 32-ch halves: half1's
// 4 float4 loads are issued BEFORE half0's compute (~1536 VALU-cyc/wave
// hides HBM latency), then barrier -> LDS write -> barrier -> compute.
// Peak live regs ~= acc(24) + held-f(16) + addr -> ~65 VGPR, safely under
// the launch_bounds(256,3) cap of 85 (R13 spilled at 84/85 -> 1.09 GB
// scratch traffic; this is the spill-free retest of the same hypothesis).
// fbuf stride 36 floats: (lane*144B mod 128B) -> 8 distinct 16B slots =
// wave64 b128 conflict-free floor. qbuf reads are uniform broadcasts.
__global__ __launch_bounds__(256, 3) void score_kernel(const float* __restrict__ x,
    const float* __restrict__ qk, float* __restrict__ part) {
  const int bm = blockIdx.x & 31;
  const int b  = blockIdx.x >> 5;
  const int kc = blockIdx.y;          // 0..11
  const int tid = threadIdx.x;

  __shared__ __align__(16) float fbuf[2][MT_][36];   // 2 x 128 rows x 32 ch (+4 pad)
  __shared__ __align__(16) float qbuf[S_][68];       // 48 x 64 ch (+4 pad)

  const char* xb = (const char*)(x + ((size_t)b * N_ + T_ + bm * MT_) * C_ + kc * KC_);
  const char* qb = (const char*)(qk + (size_t)b * S_ * C_ + kc * KC_);

  // f half staging: 128 rows x 8 chunks = 1024 float4/half, 4 per thread.
  // r_i = (tid>>3) + 32*i, j = tid&7  (8 lanes/row -> 128 B contiguous runs)
  const unsigned fr0 = tid >> 3, fj = tid & 7;
  // q staging: 768 float4, 3 per thread. s_i = (tid>>4) + 16*i, j = tid&15
  const unsigned qs = tid >> 4, qj = tid & 15;

  float4 hA[4];
  #pragma unroll
  for (int i = 0; i < 4; ++i)
    hA[i] = *(const float4*)(xb + (size_t)(fr0 + 32 * i) * (C_ * 4) + fj * 16);
  {
    float4 qv[3];
    #pragma unroll
    for (int i = 0; i < 3; ++i)
      qv[i] = *(const float4*)(qb + (size_t)(qs + 16 * i) * (C_ * 4) + qj * 16);
    #pragma unroll
    for (int i = 0; i < 4; ++i)
      *(float4*)&fbuf[0][fr0 + 32 * i][fj * 4] = hA[i];
    #pragma unroll
    for (int i = 0; i < 3; ++i)
      *(float4*)&qbuf[qs + 16 * i][qj * 4] = qv[i];
  }
  // issue f half1 (held across half0 compute; 16 VGPR)
  #pragma unroll
  for (int i = 0; i < 4; ++i)
    hA[i] = *(const float4*)(xb + (size_t)(fr0 + 32 * i) * (C_ * 4) + 128 + fj * 16);
  __syncthreads();

  const int w = tid >> 6;
  const int lane = tid & 63;
  const int s0 = w * 12;               // this wave's s range

  float acc[12][2];
  #pragma unroll
  for (int si = 0; si < 12; ++si) {
    acc[si][0] = 0.f; acc[si][1] = 0.f;
  }

  // ---- compute half 0 (channels 0..31) ----
  #pragma unroll 2
  for (int j = 0; j < 8; ++j) {
    float4 f0 = *(const float4*)&fbuf[0][lane     ][j * 4];
    float4 f1 = *(const float4*)&fbuf[0][lane + 64][j * 4];
    #pragma unroll
    for (int si = 0; si < 12; ++si) {
      float4 q = *(const float4*)&qbuf[s0 + si][j * 4];
      acc[si][0] += f0.x * q.x + f0.y * q.y + f0.z * q.z + f0.w * q.w;
      acc[si][1] += f1.x * q.x + f1.y * q.y + f1.z * q.z + f1.w * q.w;
    }
  }
  __syncthreads();
  #pragma unroll
  for (int i = 0; i < 4; ++i)
    *(float4*)&fbuf[1][fr0 + 32 * i][fj * 4] = hA[i];
  __syncthreads();
  // ---- compute half 1 (channels 32..63) ----
  #pragma unroll 2
  for (int j = 0; j < 8; ++j) {
    float4 f0 = *(const float4*)&fbuf[1][lane     ][j * 4];
    float4 f1 = *(const float4*)&fbuf[1][lane + 64][j * 4];
    #pragma unroll
    for (int si = 0; si < 12; ++si) {
      float4 q = *(const float4*)&qbuf[s0 + si][32 + j * 4];
      acc[si][0] += f0.x * q.x + f0.y * q.y + f0.z * q.z + f0.w * q.w;
      acc[si][1] += f1.x * q.x + f1.y * q.y + f1.z * q.z + f1.w * q.w;
    }
  }

  const int m0 = bm * MT_;
  #pragma unroll
  for (int si = 0; si < 12; ++si) {
    float* pp = part + (((size_t)kc * B_ + b) * S_ + (s0 + si)) * M_ + m0 + lane;
    pp[0]  = acc[si][0];
    pp[64] = acc[si][1];
  }
}

// ---- K3: sum k-split partials over a 512-m segment + segment top-2 candidate.
// block = (b*S+s)*8 + seg; 256 threads, 2 m each.
__global__ __launch_bounds__(256) void reduce_kernel(const float* __restrict__ part,
                                                     float* __restrict__ cand) {
  const int seg = blockIdx.x & 7;
  const int bs = blockIdx.x >> 3;     // b*S + s
  const int tid = threadIdx.x;
  const size_t kstride = (size_t)B_ * S_ * M_;
  const float* p0 = part + (size_t)bs * M_ + seg * 512 + tid * 2;
  float a0 = 0.f, a1 = 0.f;
  #pragma unroll
  for (int kc = 0; kc < KS_; ++kc) {
    float2 v = *(const float2*)(p0 + kc * kstride);
    a0 += v.x; a1 += v.y;
  }
  const int mA = seg * 512 + tid * 2;
  float v1, v2; int i1, i2;
  if (better(a0, mA, a1, mA + 1)) { v1 = a0; i1 = mA; v2 = a1; i2 = mA + 1; }
  else                            { v1 = a1; i1 = mA + 1; v2 = a0; i2 = mA; }
  #pragma unroll
  for (int off = 1; off < 64; off <<= 1) {
    float ov1 = __shfl_xor(v1, off);
    int   oi1 = __shfl_xor(i1, off);
    float ov2 = __shfl_xor(v2, off);
    int   oi2 = __shfl_xor(i2, off);
    merge2(v1, i1, v2, i2, ov1, oi1, ov2, oi2);
  }
  __shared__ float cbuf[4][4];
  const int w = tid >> 6, lane = tid & 63;
  if (lane == 0) {
    cbuf[w][0] = v1; ((int*)cbuf[w])[1] = i1;
    cbuf[w][2] = v2; ((int*)cbuf[w])[3] = i2;
  }
  __syncthreads();
  if (tid == 0) {
    for (int ww = 1; ww < 4; ++ww)
      merge2(v1, i1, v2, i2, cbuf[ww][0], ((int*)cbuf[ww])[1],
             cbuf[ww][2], ((int*)cbuf[ww])[3]);
    ((float4*)cand)[blockIdx.x] =
        make_float4(v1, __int_as_float(i1), v2, __int_as_float(i2));
  }
}

// ---- K4a: merge 8 candidates -> top-2 + softmax; v-projection on combined
// row. Writes selws[bs*72 + {0..63: attnh, 64..67: i1,i2,w1,w2}].
// block = (b,s), 96 blocks.
__global__ __launch_bounds__(256) void gatherA_kernel(const float* __restrict__ x,
    const float* __restrict__ kv_w, const float* __restrict__ cand,
    float* __restrict__ selws) {
  const int h = blockIdx.x % H_;
  const int b = blockIdx.x / S_;
  const int tid = threadIdx.x;

  __shared__ __align__(16) float fc[C_];
  __shared__ float red[256];
  __shared__ float sel[4];

  if (tid < 8) {
    float4 cv = ((const float4*)cand)[blockIdx.x * 8 + tid];
    float v1 = cv.x, v2 = cv.z;
    int i1 = __float_as_int(cv.y), i2 = __float_as_int(cv.w);
    #pragma unroll
    for (int off = 1; off < 8; off <<= 1) {
      float ov1 = __shfl_xor(v1, off);
      int   oi1 = __shfl_xor(i1, off);
      float ov2 = __shfl_xor(v2, off);
      int   oi2 = __shfl_xor(i2, off);
      merge2(v1, i1, v2, i2, ov1, oi1, ov2, oi2);
    }
    if (tid == 0) {
      float w1 = 1.f / (1.f + expf(v2 - v1));
      ((int*)sel)[0] = i1; ((int*)sel)[1] = i2;
      sel[2] = w1; sel[3] = 1.f - w1;
    }
  }
  __syncthreads();
  const int i1 = ((const int*)sel)[0];
  const int i2 = ((const int*)sel)[1];
  const float w1 = sel[2], w2 = sel[3];

  const float* r0 = x + ((size_t)b * N_ + T_ + i1) * C_;
  const float* r1 = x + ((size_t)b * N_ + T_ + i2) * C_;
  for (int i = tid; i < C_; i += 256)
    fc[i] = w1 * r0[i] + w2 * r1[i];
  __syncthreads();

  {
    const int j = tid & 63, pt = tid >> 6;
    const float4* kr4 = (const float4*)(kv_w + ((size_t)(C_ + h * D_ + j)) * C_ + pt * 192);
    const float4* fc4 = (const float4*)(&fc[pt * 192]);
    float a = 0.f;
    #pragma unroll 8
    for (int c4 = 0; c4 < 48; ++c4) {
      float4 kv = kr4[c4], fv = fc4[c4];
      a += kv.x * fv.x + kv.y * fv.y + kv.z * fv.z + kv.w * fv.w;
    }
    red[tid] = a;
  }
  __syncthreads();
  if (tid < 64)
    selws[(size_t)blockIdx.x * 72 + tid] =
        red[tid] + red[tid + 64] + red[tid + 128] + red[tid + 192];
  else if (tid < 68)
    selws[(size_t)blockIdx.x * 72 + tid] = sel[tid - 64];
}

// ---- K4b: scatter. block = (bs, oc of 8); 96 outputs each.
// token + feature contributions via atomics (out zeroed by harness).
__global__ __launch_bounds__(256) void scatter_kernel(const float* __restrict__ x,
    const float* __restrict__ experts_w, const float* __restrict__ selws,
    float* __restrict__ out) {
  const int bs = blockIdx.x >> 3, oc = blockIdx.x & 7;
  const int h = bs % H_;
  const int t = (bs / H_) % T_;
  const int b = bs / S_;
  const int tid = threadIdx.x;

  __shared__ __align__(16) float attnh[D_], g0s[D_], g1s[D_];
  __shared__ float psel[4];

  if (tid < 4) psel[tid] = selws[(size_t)bs * 72 + 64 + tid];
  __syncthreads();
  const int i1 = __float_as_int(psel[0]);
  const int i2 = __float_as_int(psel[1]);
  const float w1 = psel[2], w2 = psel[3];

  if (tid < 64) {
    attnh[tid] = selws[(size_t)bs * 72 + tid];
    g0s[tid] = x[((size_t)b * N_ + T_ + i1) * C_ + h * D_ + tid];
    g1s[tid] = x[((size_t)b * N_ + T_ + i2) * C_ + h * D_ + tid];
  }
  __syncthreads();

  if (tid < 96) {
    const int o = oc * 96 + tid;
    const float4* er4 = (const float4*)(experts_w + ((size_t)t * C_ + o) * C_ + h * D_);
    const float4* at4 = (const float4*)attnh;
    const float4* g04 = (const float4*)g0s;
    const float4* g14 = (const float4*)g1s;
    float at = 0.f, a0 = 0.f, a1 = 0.f;
    #pragma unroll
    for (int c4 = 0; c4 < 16; ++c4) {
      float4 e = er4[c4];
      float4 av = at4[c4], v0 = g04[c4], v1 = g14[c4];
      at += e.x * av.x + e.y * av.y + e.z * av.z + e.w * av.w;
      a0 += e.x * v0.x + e.y * v0.y + e.z * v0.z + e.w * v0.w;
      a1 += e.x * v1.x + e.y * v1.y + e.z * v1.z + e.w * v1.w;
    }
    atomicAdd(&out[((size_t)b * N_ + t) * C_ + o], at);
    atomicAdd(&out[((size_t)b * N_ + T_ + i1) * C_ + o], w1 * a0);
    atomicAdd(&out[((size_t)b * N_ + T_ + i2) * C_ + o], w2 * a1);
  }
}

extern "C" void kernel_launch(void* const* d_in, const int* in_sizes, int n_in,
                              void* d_out, int out_size, void* d_ws, size_t ws_size,
                              hipStream_t stream) {
  const float* x         = (const float*)d_in[0];
  const float* qs_w      = (const float*)d_in[1];
  const float* kv_w      = (const float*)d_in[2];
  const float* experts_w = (const float*)d_in[3];
  float* out = (float*)d_out;

  float* ws    = (float*)d_ws;
  float* qk    = ws;                                  // B*S*C     = 73728 floats
  float* part  = qk + (size_t)B_ * S_ * C_;           // KS*B*S*M  = 4718592
  float* cand  = part + (size_t)KS_ * B_ * S_ * M_;   // B*S*SEG*4 = 3072
  float* selws = cand + (size_t)B_ * S_ * SEG_ * 4;   // B*S*72    = 6912

  hipLaunchKernelGGL(qk_kernel,      dim3(B_ * S_),        dim3(256), 0, stream, x, qs_w, kv_w, qk);
  hipLaunchKernelGGL(score_kernel,   dim3(B_ * 32, KS_),   dim3(256), 0, stream, x, qk, part);
  hipLaunchKernelGGL(reduce_kernel,  dim3(B_ * S_ * SEG_), dim3(256), 0, stream, part, cand);
  hipLaunchKernelGGL(gatherA_kernel, dim3(B_ * S_),        dim3(256), 0, stream, x, kv_w, cand, selws);
  hipLaunchKernelGGL(scatter_kernel, dim3(B_ * S_ * 8),    dim3(256), 0, stream, x, experts_w, selws, out);
}

// Round 15
// 137.355 us; speedup vs baseline: 3.8237x; 1.0474x over previous
//
#include <hip/hip_runtime.h>
#include <math.h>

#define B_ 2
#define N_ 4100
#define C_ 768
#define T_ 4
#define H_ 12
#define D_ 64
#define M_ 4096
#define S_ 48          // T_*H_
#define KS_ 12         // k-split for score GEMM
#define KC_ 64         // channels per k-split chunk
#define NJ_ 16         // KC_/4 : 16B chunks per row per split
#define MT_ 128        // m rows per score block
#define SEG_ 8         // m-segments per (b,s) in reduce
#define SCALE 0.125f   // d^-0.5 = 1/8

// ---- top-2 helpers (ties -> lowest index, matching jax.lax.top_k) ----
__device__ __forceinline__ bool better(float va, int ia, float vb, int ib) {
  return (va > vb) || (va == vb && ia < ib);
}

__device__ __forceinline__ void merge2(float& v1, int& i1, float& v2, int& i2,
                                       float ov1, int oi1, float ov2, int oi2) {
  if (better(ov1, oi1, v1, i1)) {
    float tv; int ti;
    tv = v1; ti = i1; v1 = ov1; i1 = oi1; ov1 = tv; oi1 = ti;
    tv = v2; ti = i2; v2 = ov2; i2 = oi2; ov2 = tv; oi2 = ti;
  }
  if (better(ov1, oi1, v2, i2)) { v2 = ov1; i2 = oi1; }
}

// ---- K1: qk only (out arrives zeroed by the harness each iteration).
// qk[b*S+s][c] = sum_j q[b,s,j] * kv_w[j][c] * SCALE  (k-proj folded into q)
__global__ __launch_bounds__(256) void qk_kernel(const float* __restrict__ x,
    const float* __restrict__ qs_w, const float* __restrict__ kv_w,
    float* __restrict__ qk) {
  const int blk = blockIdx.x;
  const int tid = threadIdx.x;
  const int h = blk % H_;
  const int t = (blk / H_) % T_;
  const int b = blk / S_;
  __shared__ float xs[C_];
  __shared__ float red[256];
  __shared__ float qseg[D_];
  for (int i = tid; i < C_; i += 256) xs[i] = x[((size_t)b * N_ + t) * C_ + i];
  __syncthreads();
  {
    const int j = tid & 63;
    const int pt = tid >> 6;          // 4 parts of 192 channels
    const float* wr = qs_w + ((size_t)t * C_ + h * D_ + j) * C_ + pt * 192;
    float a = 0.f;
    for (int c = 0; c < 192; ++c) a += xs[pt * 192 + c] * wr[c];
    red[tid] = a;
  }
  __syncthreads();
  if (tid < 64)
    qseg[tid] = (red[tid] + red[tid + 64] + red[tid + 128] + red[tid + 192]) * SCALE;
  __syncthreads();
  for (int c = tid; c < C_; c += 256) {
    float a = 0.f;
    #pragma unroll 8
    for (int j = 0; j < 64; ++j) a += qseg[j] * kv_w[((size_t)(h * D_ + j)) * C_ + c];
    qk[(size_t)blk * C_ + c] = a;
  }
}

// ---- K2: partial scores. block = (b, mtile of 128 m) x kc (12 splits of 64 ch).
// grid 768 = exactly 3 blocks/CU; acc tile Rm=2 x Rs=12, VGPR ~60 -> no spill.
// fbuf stride 68 floats (17 float4, odd) -> per-lane b128 conflict-free floor;
// q reads are uniform broadcasts. (Verified best config, ~22 us. Falsified
// alternatives: bigger tiles R10/R11, dbuf overlap R13/R14, occupancy R5.)
__global__ __launch_bounds__(256, 3) void score_kernel(const float* __restrict__ x,
    const float* __restrict__ qk, float* __restrict__ part) {
  const int bm = blockIdx.x & 31;
  const int b  = blockIdx.x >> 5;
  const int kc = blockIdx.y;          // 0..11
  const int tid = threadIdx.x;

  __shared__ __align__(16) float fbuf[MT_][68];   // 128 x 64ch (+4 pad)
  __shared__ __align__(16) float qbuf[S_][KC_];   // 48 x 64ch

  // stage f: 128 rows x 16 chunks = 2048 float4, 8 per thread, shift-only idx
  {
    const char* xb = (const char*)(x + ((size_t)b * N_ + T_ + bm * MT_) * C_ + kc * KC_);
    #pragma unroll
    for (int i = 0; i < 8; ++i) {
      unsigned g = i * 256 + tid;       // 0..2047
      unsigned r = g >> 4, j = g & 15;
      *(float4*)&fbuf[r][j * 4] = *(const float4*)(xb + (size_t)r * (C_ * 4) + j * 16);
    }
  }
  // stage q: 48 rows x 16 chunks = 768 float4, 3 per thread exact
  {
    const char* qb = (const char*)(qk + (size_t)b * S_ * C_ + kc * KC_);
    #pragma unroll
    for (int i = 0; i < 3; ++i) {
      unsigned g = i * 256 + tid;       // 0..767
      unsigned s = g >> 4, j = g & 15;
      *(float4*)&qbuf[s][j * 4] = *(const float4*)(qb + (size_t)s * (C_ * 4) + j * 16);
    }
  }
  __syncthreads();

  const int w = tid >> 6;
  const int lane = tid & 63;
  const int s0 = w * 12;               // this wave's s range

  float acc[12][2];
  #pragma unroll
  for (int si = 0; si < 12; ++si) {
    acc[si][0] = 0.f; acc[si][1] = 0.f;
  }

  #pragma unroll 2
  for (int j = 0; j < NJ_; ++j) {
    float4 f0 = *(const float4*)&fbuf[lane     ][j * 4];
    float4 f1 = *(const float4*)&fbuf[lane + 64][j * 4];
    #pragma unroll
    for (int si = 0; si < 12; ++si) {
      float4 q = *(const float4*)&qbuf[s0 + si][j * 4];
      acc[si][0] += f0.x * q.x + f0.y * q.y + f0.z * q.z + f0.w * q.w;
      acc[si][1] += f1.x * q.x + f1.y * q.y + f1.z * q.z + f1.w * q.w;
    }
  }

  const int m0 = bm * MT_;
  #pragma unroll
  for (int si = 0; si < 12; ++si) {
    float* pp = part + (((size_t)kc * B_ + b) * S_ + (s0 + si)) * M_ + m0 + lane;
    pp[0]  = acc[si][0];
    pp[64] = acc[si][1];
  }
}

// ---- K3: sum k-split partials over a 512-m segment + segment top-2 candidate.
// block = (b*S+s)*8 + seg; 256 threads, 2 m each.
__global__ __launch_bounds__(256) void reduce_kernel(const float* __restrict__ part,
                                                     float* __restrict__ cand) {
  const int seg = blockIdx.x & 7;
  const int bs = blockIdx.x >> 3;     // b*S + s
  const int tid = threadIdx.x;
  const size_t kstride = (size_t)B_ * S_ * M_;
  const float* p0 = part + (size_t)bs * M_ + seg * 512 + tid * 2;
  float a0 = 0.f, a1 = 0.f;
  #pragma unroll
  for (int kc = 0; kc < KS_; ++kc) {
    float2 v = *(const float2*)(p0 + kc * kstride);
    a0 += v.x; a1 += v.y;
  }
  const int mA = seg * 512 + tid * 2;
  float v1, v2; int i1, i2;
  if (better(a0, mA, a1, mA + 1)) { v1 = a0; i1 = mA; v2 = a1; i2 = mA + 1; }
  else                            { v1 = a1; i1 = mA + 1; v2 = a0; i2 = mA; }
  #pragma unroll
  for (int off = 1; off < 64; off <<= 1) {
    float ov1 = __shfl_xor(v1, off);
    int   oi1 = __shfl_xor(i1, off);
    float ov2 = __shfl_xor(v2, off);
    int   oi2 = __shfl_xor(i2, off);
    merge2(v1, i1, v2, i2, ov1, oi1, ov2, oi2);
  }
  __shared__ float cbuf[4][4];
  const int w = tid >> 6, lane = tid & 63;
  if (lane == 0) {
    cbuf[w][0] = v1; ((int*)cbuf[w])[1] = i1;
    cbuf[w][2] = v2; ((int*)cbuf[w])[3] = i2;
  }
  __syncthreads();
  if (tid == 0) {
    for (int ww = 1; ww < 4; ++ww)
      merge2(v1, i1, v2, i2, cbuf[ww][0], ((int*)cbuf[ww])[1],
             cbuf[ww][2], ((int*)cbuf[ww])[3]);
    ((float4*)cand)[blockIdx.x] =
        make_float4(v1, __int_as_float(i1), v2, __int_as_float(i2));
  }
}

// ---- K4a: merge 8 candidates -> top-2 + softmax; v-projection on combined
// row. Writes selws[bs*72 + {0..63: attnh, 64..67: i1,i2,w1,w2}].
// block = (b,s), 96 blocks.
__global__ __launch_bounds__(256) void gatherA_kernel(const float* __restrict__ x,
    const float* __restrict__ kv_w, const float* __restrict__ cand,
    float* __restrict__ selws) {
  const int h = blockIdx.x % H_;
  const int b = blockIdx.x / S_;
  const int tid = threadIdx.x;

  __shared__ __align__(16) float fc[C_];
  __shared__ float red[256];
  __shared__ float sel[4];

  if (tid < 8) {
    float4 cv = ((const float4*)cand)[blockIdx.x * 8 + tid];
    float v1 = cv.x, v2 = cv.z;
    int i1 = __float_as_int(cv.y), i2 = __float_as_int(cv.w);
    #pragma unroll
    for (int off = 1; off < 8; off <<= 1) {
      float ov1 = __shfl_xor(v1, off);
      int   oi1 = __shfl_xor(i1, off);
      float ov2 = __shfl_xor(v2, off);
      int   oi2 = __shfl_xor(i2, off);
      merge2(v1, i1, v2, i2, ov1, oi1, ov2, oi2);
    }
    if (tid == 0) {
      float w1 = 1.f / (1.f + expf(v2 - v1));
      ((int*)sel)[0] = i1; ((int*)sel)[1] = i2;
      sel[2] = w1; sel[3] = 1.f - w1;
    }
  }
  __syncthreads();
  const int i1 = ((const int*)sel)[0];
  const int i2 = ((const int*)sel)[1];
  const float w1 = sel[2], w2 = sel[3];

  const float* r0 = x + ((size_t)b * N_ + T_ + i1) * C_;
  const float* r1 = x + ((size_t)b * N_ + T_ + i2) * C_;
  for (int i = tid; i < C_; i += 256)
    fc[i] = w1 * r0[i] + w2 * r1[i];
  __syncthreads();

  {
    const int j = tid & 63, pt = tid >> 6;
    const float4* kr4 = (const float4*)(kv_w + ((size_t)(C_ + h * D_ + j)) * C_ + pt * 192);
    const float4* fc4 = (const float4*)(&fc[pt * 192]);
    float a = 0.f;
    #pragma unroll 8
    for (int c4 = 0; c4 < 48; ++c4) {
      float4 kv = kr4[c4], fv = fc4[c4];
      a += kv.x * fv.x + kv.y * fv.y + kv.z * fv.z + kv.w * fv.w;
    }
    red[tid] = a;
  }
  __syncthreads();
  if (tid < 64)
    selws[(size_t)blockIdx.x * 72 + tid] =
        red[tid] + red[tid + 64] + red[tid + 128] + red[tid + 192];
  else if (tid < 68)
    selws[(size_t)blockIdx.x * 72 + tid] = sel[tid - 64];
}

// ---- K4b: scatter. block = (bs, oc of 8); 96 outputs each.
// token + feature contributions via atomics (out zeroed by harness).
__global__ __launch_bounds__(256) void scatter_kernel(const float* __restrict__ x,
    const float* __restrict__ experts_w, const float* __restrict__ selws,
    float* __restrict__ out) {
  const int bs = blockIdx.x >> 3, oc = blockIdx.x & 7;
  const int h = bs % H_;
  const int t = (bs / H_) % T_;
  const int b = bs / S_;
  const int tid = threadIdx.x;

  __shared__ __align__(16) float attnh[D_], g0s[D_], g1s[D_];
  __shared__ float psel[4];

  if (tid < 4) psel[tid] = selws[(size_t)bs * 72 + 64 + tid];
  __syncthreads();
  const int i1 = __float_as_int(psel[0]);
  const int i2 = __float_as_int(psel[1]);
  const float w1 = psel[2], w2 = psel[3];

  if (tid < 64) {
    attnh[tid] = selws[(size_t)bs * 72 + tid];
    g0s[tid] = x[((size_t)b * N_ + T_ + i1) * C_ + h * D_ + tid];
    g1s[tid] = x[((size_t)b * N_ + T_ + i2) * C_ + h * D_ + tid];
  }
  __syncthreads();

  if (tid < 96) {
    const int o = oc * 96 + tid;
    const float4* er4 = (const float4*)(experts_w + ((size_t)t * C_ + o) * C_ + h * D_);
    const float4* at4 = (const float4*)attnh;
    const float4* g04 = (const float4*)g0s;
    const float4* g14 = (const float4*)g1s;
    float at = 0.f, a0 = 0.f, a1 = 0.f;
    #pragma unroll
    for (int c4 = 0; c4 < 16; ++c4) {
      float4 e = er4[c4];
      float4 av = at4[c4], v0 = g04[c4], v1 = g14[c4];
      at += e.x * av.x + e.y * av.y + e.z * av.z + e.w * av.w;
      a0 += e.x * v0.x + e.y * v0.y + e.z * v0.z + e.w * v0.w;
      a1 += e.x * v1.x + e.y * v1.y + e.z * v1.z + e.w * v1.w;
    }
    atomicAdd(&out[((size_t)b * N_ + t) * C_ + o], at);
    atomicAdd(&out[((size_t)b * N_ + T_ + i1) * C_ + o], w1 * a0);
    atomicAdd(&out[((size_t)b * N_ + T_ + i2) * C_ + o], w2 * a1);
  }
}

extern "C" void kernel_launch(void* const* d_in, const int* in_sizes, int n_in,
                              void* d_out, int out_size, void* d_ws, size_t ws_size,
                              hipStream_t stream) {
  const float* x         = (const float*)d_in[0];
  const float* qs_w      = (const float*)d_in[1];
  const float* kv_w      = (const float*)d_in[2];
  const float* experts_w = (const float*)d_in[3];
  float* out = (float*)d_out;

  float* ws    = (float*)d_ws;
  float* qk    = ws;                                  // B*S*C     = 73728 floats
  float* part  = qk + (size_t)B_ * S_ * C_;           // KS*B*S*M  = 4718592
  float* cand  = part + (size_t)KS_ * B_ * S_ * M_;   // B*S*SEG*4 = 3072
  float* selws = cand + (size_t)B_ * S_ * SEG_ * 4;   // B*S*72    = 6912

  hipLaunchKernelGGL(qk_kernel,      dim3(B_ * S_),        dim3(256), 0, stream, x, qs_w, kv_w, qk);
  hipLaunchKernelGGL(score_kernel,   dim3(B_ * 32, KS_),   dim3(256), 0, stream, x, qk, part);
  hipLaunchKernelGGL(reduce_kernel,  dim3(B_ * S_ * SEG_), dim3(256), 0, stream, part, cand);
  hipLaunchKernelGGL(gatherA_kernel, dim3(B_ * S_),        dim3(256), 0, stream, x, kv_w, cand, selws);
  hipLaunchKernelGGL(scatter_kernel, dim3(B_ * S_ * 8),    dim3(256), 0, stream, x, experts_w, selws, out);
}